// Round 13
// baseline (193.814 us; speedup 1.0000x reference)
//
#include <hip/hip_runtime.h>
#include <math.h>

#define NROWS   16384
#define NBOOKS  128
#define NWORDS  64
#define LWORD   32
#define DIMS    4096
#define T2K     28.8539008177792681472f   /* 20 * log2(e) */
#define Z_ELEMS 67108864ull               /* 16384*4096   */
#define NIT     8                         /* row tiles per block */

typedef __attribute__((ext_vector_type(8))) short s16x8;
typedef __attribute__((ext_vector_type(4))) float f32x4;
typedef __attribute__((ext_vector_type(4))) unsigned int u32x4;

/* ws layout (bytes) */
#define CBT_OFF  0u           /* f32 [128][64][32] np-normalized codewords       */
#define C2T_OFF  1048576u     /* f32 [128][64]                                   */
#define FR_OFF   1114112u     /* frags: [book][wb*4+slot][lane] s16x8, 16KB/book */
#define CTR_OFF  3211264u     /* u32 rescan counter                              */
#define LIST_OFF 3211392u     /* u32[131072] packed (row<<7)|b                   */
#define LIST_CAP 131072u

__device__ __forceinline__ unsigned short f2bf(float f) {
    unsigned int u = __float_as_uint(f);
    unsigned int r = (u + 0x7FFFu + ((u >> 16) & 1u)) >> 16;   /* RNE */
    return (unsigned short)r;
}
__device__ __forceinline__ float bf2f(unsigned short s) {
    return __uint_as_float(((unsigned int)s) << 16);
}
__device__ __forceinline__ unsigned int cvtpk_bf16(float lo, float hi) {
    unsigned int r;
    asm("v_cvt_pk_bf16_f32 %0, %1, %2" : "=v"(r) : "v"(lo), "v"(hi));  /* RNE */
    return r;
}

/* numpy pairwise-sum replica for n=32 f32 (exact order, no contraction) */
__device__ __forceinline__ float np_sum32(const float* a) {
#pragma clang fp contract(off)
    float r0 = a[0], r1 = a[1], r2 = a[2], r3 = a[3];
    float r4 = a[4], r5 = a[5], r6 = a[6], r7 = a[7];
    r0 += a[8];  r1 += a[9];  r2 += a[10]; r3 += a[11];
    r4 += a[12]; r5 += a[13]; r6 += a[14]; r7 += a[15];
    r0 += a[16]; r1 += a[17]; r2 += a[18]; r3 += a[19];
    r4 += a[20]; r5 += a[21]; r6 += a[22]; r7 += a[23];
    r0 += a[24]; r1 += a[25]; r2 += a[26]; r3 += a[27];
    r4 += a[28]; r5 += a[29]; r6 += a[30]; r7 += a[31];
    return ((r0 + r1) + (r2 + r3)) + ((r4 + r5) + (r6 + r7));
}

/* ---------- kernel 1: fused np-exact normalize + frag build (verified r12) ---------- */
__global__ __launch_bounds__(64) void prepC_kernel(const float* __restrict__ C,
                                                   float* __restrict__ cbT,
                                                   float* __restrict__ c2T,
                                                   s16x8* __restrict__ fr,
                                                   unsigned int* __restrict__ ctr) {
    __shared__ float cb_s[NWORDS][33];
    __shared__ float c2_s[NWORDS];
    int b = blockIdx.x;
    int w = threadIdx.x;
    if (b == 0 && w == 0) ctr[0] = 0u;

    float cb[LWORD];
    float c2;
    {
#pragma clang fp contract(off)
        const float* src = C + (size_t)w * DIMS + b * LWORD;
        float v[LWORD];
        #pragma unroll
        for (int q = 0; q < 8; ++q)
            *(float4*)&v[4 * q] = *(const float4*)&src[4 * q];
        float sq[LWORD];
        #pragma unroll
        for (int l = 0; l < LWORD; ++l) sq[l] = v[l] * v[l];
        float nrm = fmaxf(sqrtf(np_sum32(sq)), 1e-12f);
        #pragma unroll
        for (int l = 0; l < LWORD; ++l) cb[l] = v[l] / nrm;
        float sq2[LWORD];
        #pragma unroll
        for (int l = 0; l < LWORD; ++l) sq2[l] = cb[l] * cb[l];
        c2 = np_sum32(sq2);
    }
    float* dst = cbT + ((size_t)b * NWORDS + w) * LWORD;
    #pragma unroll
    for (int q = 0; q < 8; ++q)
        *(float4*)&dst[4 * q] = *(const float4*)&cb[4 * q];
    c2T[b * NWORDS + w] = c2;
    #pragma unroll
    for (int l = 0; l < LWORD; ++l) cb_s[w][l] = cb[l];
    c2_s[w] = c2;
    __syncthreads();

    int lr = w & 15, lh = w >> 4;
    s16x8* frb = fr + (size_t)b * 1024;       /* 16KB per book */
    #pragma unroll
    for (int wb = 0; wb < 4; ++wb) {
        s16x8 ch8, cl8, a28;
        #pragma unroll
        for (int i = 0; i < 8; ++i) {
            float f = cb_s[wb * 16 + lr][lh * 8 + i];
            unsigned short hh = f2bf(f);
            ch8[i] = (short)hh;
            cl8[i] = (short)f2bf(f - bf2f(hh));
            a28[i] = (short)f2bf(cb_s[(wb & 1) * 32 + lh * 8 + i][(wb >> 1) * 16 + lr]);
        }
        f32x4 civ = {-0.5f * c2_s[wb * 16 + lh * 4 + 0],
                     -0.5f * c2_s[wb * 16 + lh * 4 + 1],
                     -0.5f * c2_s[wb * 16 + lh * 4 + 2],
                     -0.5f * c2_s[wb * 16 + lh * 4 + 3]};
        frb[(wb * 4 + 0) * 64 + w] = ch8;
        frb[(wb * 4 + 1) * 64 + w] = cl8;
        frb[(wb * 4 + 2) * 64 + w] = a28;
        frb[(wb * 4 + 3) * 64 + w] = __builtin_bit_cast(s16x8, civ);
    }
}

/* ---------- kernel 2: persistent per-book blocks, NIT row-tiles, x-prefetch ---------- */
__global__ __launch_bounds__(512, 8) void softpq_mfma(const float* __restrict__ x,
                                                      const s16x8* __restrict__ fr,
                                                      unsigned int* __restrict__ ctr,
                                                      unsigned int* __restrict__ list,
                                                      float* __restrict__ out) {
    __shared__ __align__(16) s16x8 frag_s[1024];                 /* 16384 B */
    __shared__ __align__(16) unsigned short ps_s[8][16][72];     /* 18432 B */

    /* blockIdx = book*16 + chunk: chunk%8 fixes the XCD, so the same row-range
       across all books shares one XCD's L2 (idx-line write merging). */
    int bk    = blockIdx.x;
    int b     = bk >> 4;
    int chunk = bk & 15;
    int t     = threadIdx.x;
    int lane = t & 63, wid = t >> 6;
    int h = lane >> 4, c = lane & 15;
    int row0 = chunk * (NIT * 128) + wid * 16 + c;

    /* iter-0 x prefetch first (HBM latency overlaps staging + barrier) */
    const float* xp = x + (size_t)row0 * DIMS + b * LWORD + h * 8;
    float4 nxa = *(const float4*)xp;
    float4 nxb = *(const float4*)(xp + 4);

    /* stage book's 16KB frag record once: 512 thr x 32B, conflict-free */
    {
        const s16x8* g = fr + (size_t)b * 1024 + t * 2;
        s16x8 g0 = g[0];
        s16x8 g1 = g[1];
        frag_s[t * 2]     = g0;
        frag_s[t * 2 + 1] = g1;
    }
    __syncthreads();

    #pragma unroll 1
    for (int it = 0; it < NIT; ++it) {
        float4 xa = nxa, xb = nxb;
        if (it + 1 < NIT) {               /* prefetch next tile's x */
            const float* nxp = xp + (size_t)(it + 1) * 128 * DIMS;
            nxa = *(const float4*)nxp;
            nxb = *(const float4*)(nxp + 4);
        }
        int row = row0 + it * 128;

        /* split x into bf16 hi + residual (verbatim) */
        float xf[8] = {xa.x, xa.y, xa.z, xa.w, xb.x, xb.y, xb.z, xb.w};
        unsigned int xhu[4], xlu[4];
        #pragma unroll
        for (int j = 0; j < 4; ++j) {
            float f0 = xf[2 * j], f1 = xf[2 * j + 1];
            unsigned int ph = cvtpk_bf16(f0, f1);
            float h0 = __uint_as_float(ph << 16);
            float h1 = __uint_as_float(ph & 0xffff0000u);
            xhu[j] = ph;
            xlu[j] = cvtpk_bf16(f0 - h0, f1 - h1);
        }
        u32x4 thv = {xhu[0], xhu[1], xhu[2], xhu[3]};
        u32x4 tlv = {xlu[0], xlu[1], xlu[2], xlu[3]};
        s16x8 xhv = __builtin_bit_cast(s16x8, thv);
        s16x8 xlv = __builtin_bit_cast(s16x8, tlv);

        /* 12 S-MFMAs, frags from LDS; acc = dot - c2/2 (verbatim) */
        f32x4 acc[4];
        __builtin_amdgcn_s_setprio(1);
        #pragma unroll
        for (int wb = 0; wb < 4; ++wb) {
            s16x8 chf = frag_s[(wb * 4 + 0) * 64 + lane];
            s16x8 clf = frag_s[(wb * 4 + 1) * 64 + lane];
            f32x4 a   = __builtin_bit_cast(f32x4, frag_s[(wb * 4 + 3) * 64 + lane]);
            a = __builtin_amdgcn_mfma_f32_16x16x32_bf16(chf, xhv, a, 0, 0, 0);
            a = __builtin_amdgcn_mfma_f32_16x16x32_bf16(chf, xlv, a, 0, 0, 0);
            a = __builtin_amdgcn_mfma_f32_16x16x32_bf16(clf, xhv, a, 0, 0, 0);
            acc[wb] = a;
        }
        __builtin_amdgcn_s_setprio(0);

        /* ---- tail: verbatim verified numerics ---- */
        float q0 = fmaxf(fmaxf(acc[0][0], acc[0][1]), acc[0][2]);
        float q1 = fmaxf(fmaxf(acc[0][3], acc[1][0]), acc[1][1]);
        float q2 = fmaxf(fmaxf(acc[1][2], acc[1][3]), acc[2][0]);
        float q3 = fmaxf(fmaxf(acc[2][1], acc[2][2]), acc[2][3]);
        float q4 = fmaxf(fmaxf(acc[3][0], acc[3][1]), acc[3][2]);
        float m1 = fmaxf(fmaxf(fmaxf(q0, q1), q2), fmaxf(fmaxf(q3, q4), acc[3][3]));
        m1 = fmaxf(m1, __shfl_xor(m1, 16));
        m1 = fmaxf(m1, __shfl_xor(m1, 32));

        float thr = m1 - 2e-4f;
        int cnt = 0;
        #pragma unroll
        for (int wb = 0; wb < 4; ++wb)
            #pragma unroll
            for (int r = 0; r < 4; ++r) cnt += (acc[wb][r] > thr) ? 1 : 0;
        cnt += __shfl_xor(cnt, 16);
        cnt += __shfl_xor(cnt, 32);

        int wsel = 9999;
        #pragma unroll
        for (int wb = 0; wb < 4; ++wb)
            #pragma unroll
            for (int r = 0; r < 4; ++r)
                if (acc[wb][r] == m1) wsel = min(wsel, wb * 16 + h * 4 + r);
        wsel = min(wsel, __shfl_xor(wsel, 16));
        wsel = min(wsel, __shfl_xor(wsel, 32));

        float mqt = m1 * (-T2K);
        float p[16];
        float sum = 0.f;
        #pragma unroll
        for (int wb = 0; wb < 4; ++wb)
            #pragma unroll
            for (int r = 0; r < 4; ++r) {
                p[wb * 4 + r] = __builtin_amdgcn_exp2f(fmaf(T2K, acc[wb][r], mqt));
                sum += p[wb * 4 + r];
            }
        sum += __shfl_xor(sum, 16);
        sum += __shfl_xor(sum, 32);
        float inv = __builtin_amdgcn_rcpf(sum);

        unsigned int pku[8];
        #pragma unroll
        for (int k = 0; k < 8; ++k) pku[k] = cvtpk_bf16(p[2 * k], p[2 * k + 1]);
        #pragma unroll
        for (int wb = 0; wb < 4; ++wb) {
            uint2 w2; w2.x = pku[2 * wb]; w2.y = pku[2 * wb + 1];
            *(uint2*)&ps_s[wid][c][wb * 16 + h * 4] = w2;
        }
        s16x8 pb0 = *(const s16x8*)&ps_s[wid][c][h * 8];
        s16x8 pb1 = *(const s16x8*)&ps_s[wid][c][32 + h * 8];

        /* 4 Z-MFMAs, A-frags from LDS */
        float* zout = out + (size_t)row * DIMS + b * LWORD + h * 4;
        #pragma unroll
        for (int mb = 0; mb < 2; ++mb) {
            s16x8 a20 = frag_s[((mb * 2 + 0) * 4 + 2) * 64 + lane];
            s16x8 a21 = frag_s[((mb * 2 + 1) * 4 + 2) * 64 + lane];
            f32x4 z = {0.f, 0.f, 0.f, 0.f};
            z = __builtin_amdgcn_mfma_f32_16x16x32_bf16(a20, pb0, z, 0, 0, 0);
            z = __builtin_amdgcn_mfma_f32_16x16x32_bf16(a21, pb1, z, 0, 0, 0);
            float4 v;
            v.x = z[0] * inv; v.y = z[1] * inv; v.z = z[2] * inv; v.w = z[3] * inv;
            *(float4*)(zout + mb * 16) = v;
        }

        if (h == 0) {
            out[Z_ELEMS + (size_t)row * NBOOKS + b] = (float)wsel;
            if (cnt >= 2) {                   /* defer np-exact rescan */
                unsigned int pos = atomicAdd(ctr, 1u);
                if (pos < LIST_CAP) list[pos] = ((unsigned int)row << 7) | (unsigned int)b;
            }
        }
    }
}

/* ---------- kernel 3: wave-cooperative np-exact rescan (lane = word) ---------- */
__global__ __launch_bounds__(256) void rescan_wave(const float* __restrict__ x,
                                                   const float* __restrict__ cbT,
                                                   const float* __restrict__ c2T,
                                                   const unsigned int* __restrict__ ctr,
                                                   const unsigned int* __restrict__ list,
                                                   float* __restrict__ out) {
    unsigned int n = *ctr;
    if (n > LIST_CAP) n = LIST_CAP;
    unsigned int wgl = blockIdx.x * 4u + (threadIdx.x >> 6);
    unsigned int nw  = gridDim.x * 4u;
    int lane = threadIdx.x & 63;

    for (unsigned int i = wgl; i < n; i += nw) {
        unsigned int e = list[i];
        int row = (int)(e >> 7);
        int b   = (int)(e & 127u);

        const float* xrow = x + (size_t)row * DIMS + b * LWORD;
        float xr2[LWORD];
        #pragma unroll
        for (int q = 0; q < 8; ++q)
            *(float4*)&xr2[q * 4] = *(const float4*)(xrow + q * 4);
        float sq[LWORD];
        #pragma unroll
        for (int l = 0; l < LWORD; ++l) sq[l] = xr2[l] * xr2[l];
        float x2n = np_sum32(sq);

        const float* cw = cbT + ((size_t)b * NWORDS + lane) * LWORD;
        float cwv[LWORD];
        #pragma unroll
        for (int q = 0; q < 8; ++q)
            *(float4*)&cwv[q * 4] = *(const float4*)(cw + q * 4);
        double a0 = 0.0, a1 = 0.0, a2 = 0.0, a3 = 0.0;
        #pragma unroll
        for (int l = 0; l < 8; ++l) {
            a0 = fma((double)xr2[l],      (double)cwv[l],      a0);
            a1 = fma((double)xr2[l + 8],  (double)cwv[l + 8],  a1);
            a2 = fma((double)xr2[l + 16], (double)cwv[l + 16], a2);
            a3 = fma((double)xr2[l + 24], (double)cwv[l + 24], a3);
        }
        float xcf = (float)((a0 + a1) + (a2 + a3));
        float dnp;
        {
#pragma clang fp contract(off)
            float s1 = x2n + c2T[b * NWORDS + lane];
            float s2 = 2.0f * xcf;
            dnp = s1 - s2;
        }
        float dmin = dnp;
        dmin = fminf(dmin, __shfl_xor(dmin, 1));
        dmin = fminf(dmin, __shfl_xor(dmin, 2));
        dmin = fminf(dmin, __shfl_xor(dmin, 4));
        dmin = fminf(dmin, __shfl_xor(dmin, 8));
        dmin = fminf(dmin, __shfl_xor(dmin, 16));
        dmin = fminf(dmin, __shfl_xor(dmin, 32));
        unsigned long long ball = __ballot(dnp == dmin);
        int wbest = __ffsll((long long)ball) - 1;
        if (lane == 0)
            out[Z_ELEMS + (size_t)row * NBOOKS + b] = (float)wbest;
    }
}

extern "C" void kernel_launch(void* const* d_in, const int* in_sizes, int n_in,
                              void* d_out, int out_size, void* d_ws, size_t ws_size,
                              hipStream_t stream) {
    const float* x = (const float*)d_in[0];
    const float* C = (const float*)d_in[1];
    float* out = (float*)d_out;
    char* ws = (char*)d_ws;
    float* cbT = (float*)(ws + CBT_OFF);
    float* c2T = (float*)(ws + C2T_OFF);
    s16x8* fr  = (s16x8*)(ws + FR_OFF);
    unsigned int* ctr  = (unsigned int*)(ws + CTR_OFF);
    unsigned int* list = (unsigned int*)(ws + LIST_OFF);

    prepC_kernel<<<128, 64, 0, stream>>>(C, cbT, c2T, fr, ctr);
    softpq_mfma<<<2048, 512, 0, stream>>>(x, fr, ctr, list, out);
    rescan_wave<<<512, 256, 0, stream>>>(x, cbT, c2T, ctr, list, out);
}

// Round 14
// 154.389 us; speedup vs baseline: 1.2554x; 1.2554x over previous
//
#include <hip/hip_runtime.h>
#include <math.h>

#define NROWS   16384
#define NBOOKS  128
#define NWORDS  64
#define LWORD   32
#define DIMS    4096
#define T2K     28.8539008177792681472f   /* 20 * log2(e) */
#define Z_ELEMS 67108864ull               /* 16384*4096   */

typedef __attribute__((ext_vector_type(8))) short s16x8;
typedef __attribute__((ext_vector_type(4))) float f32x4;
typedef __attribute__((ext_vector_type(4))) unsigned int u32x4;

/* ws layout (bytes) */
#define CBT_OFF  0u           /* f32 [128][64][32] np-normalized codewords       */
#define C2T_OFF  1048576u     /* f32 [128][64]                                   */
#define FR_OFF   1114112u     /* frags: [book][wb*4+slot][lane] s16x8, 16KB/book */
#define CTR_OFF  3211264u     /* u32 rescan counter                              */
#define LIST_OFF 3211392u     /* u32[131072] packed (row<<7)|b                   */
#define LIST_CAP 131072u

__device__ __forceinline__ unsigned short f2bf(float f) {
    unsigned int u = __float_as_uint(f);
    unsigned int r = (u + 0x7FFFu + ((u >> 16) & 1u)) >> 16;   /* RNE */
    return (unsigned short)r;
}
__device__ __forceinline__ float bf2f(unsigned short s) {
    return __uint_as_float(((unsigned int)s) << 16);
}
__device__ __forceinline__ unsigned int cvtpk_bf16(float lo, float hi) {
    unsigned int r;
    asm("v_cvt_pk_bf16_f32 %0, %1, %2" : "=v"(r) : "v"(lo), "v"(hi));  /* RNE */
    return r;
}

/* numpy pairwise-sum replica for n=32 f32 (exact order, no contraction) */
__device__ __forceinline__ float np_sum32(const float* a) {
#pragma clang fp contract(off)
    float r0 = a[0], r1 = a[1], r2 = a[2], r3 = a[3];
    float r4 = a[4], r5 = a[5], r6 = a[6], r7 = a[7];
    r0 += a[8];  r1 += a[9];  r2 += a[10]; r3 += a[11];
    r4 += a[12]; r5 += a[13]; r6 += a[14]; r7 += a[15];
    r0 += a[16]; r1 += a[17]; r2 += a[18]; r3 += a[19];
    r4 += a[20]; r5 += a[21]; r6 += a[22]; r7 += a[23];
    r0 += a[24]; r1 += a[25]; r2 += a[26]; r3 += a[27];
    r4 += a[28]; r5 += a[29]; r6 += a[30]; r7 += a[31];
    return ((r0 + r1) + (r2 + r3)) + ((r4 + r5) + (r6 + r7));
}

/* ---------- kernel 1: fused np-exact normalize + frag build (verified r12) ---------- */
__global__ __launch_bounds__(64) void prepC_kernel(const float* __restrict__ C,
                                                   float* __restrict__ cbT,
                                                   float* __restrict__ c2T,
                                                   s16x8* __restrict__ fr,
                                                   unsigned int* __restrict__ ctr) {
    __shared__ float cb_s[NWORDS][33];
    __shared__ float c2_s[NWORDS];
    int b = blockIdx.x;
    int w = threadIdx.x;
    if (b == 0 && w == 0) ctr[0] = 0u;

    float cb[LWORD];
    float c2;
    {
#pragma clang fp contract(off)
        const float* src = C + (size_t)w * DIMS + b * LWORD;
        float v[LWORD];
        #pragma unroll
        for (int q = 0; q < 8; ++q)
            *(float4*)&v[4 * q] = *(const float4*)&src[4 * q];
        float sq[LWORD];
        #pragma unroll
        for (int l = 0; l < LWORD; ++l) sq[l] = v[l] * v[l];
        float nrm = fmaxf(sqrtf(np_sum32(sq)), 1e-12f);
        #pragma unroll
        for (int l = 0; l < LWORD; ++l) cb[l] = v[l] / nrm;
        float sq2[LWORD];
        #pragma unroll
        for (int l = 0; l < LWORD; ++l) sq2[l] = cb[l] * cb[l];
        c2 = np_sum32(sq2);
    }
    float* dst = cbT + ((size_t)b * NWORDS + w) * LWORD;
    #pragma unroll
    for (int q = 0; q < 8; ++q)
        *(float4*)&dst[4 * q] = *(const float4*)&cb[4 * q];
    c2T[b * NWORDS + w] = c2;
    #pragma unroll
    for (int l = 0; l < LWORD; ++l) cb_s[w][l] = cb[l];
    c2_s[w] = c2;
    __syncthreads();

    int lr = w & 15, lh = w >> 4;
    s16x8* frb = fr + (size_t)b * 1024;       /* 16KB per book */
    #pragma unroll
    for (int wb = 0; wb < 4; ++wb) {
        s16x8 ch8, cl8, a28;
        #pragma unroll
        for (int i = 0; i < 8; ++i) {
            float f = cb_s[wb * 16 + lr][lh * 8 + i];
            unsigned short hh = f2bf(f);
            ch8[i] = (short)hh;
            cl8[i] = (short)f2bf(f - bf2f(hh));
            a28[i] = (short)f2bf(cb_s[(wb & 1) * 32 + lh * 8 + i][(wb >> 1) * 16 + lr]);
        }
        f32x4 civ = {-0.5f * c2_s[wb * 16 + lh * 4 + 0],
                     -0.5f * c2_s[wb * 16 + lh * 4 + 1],
                     -0.5f * c2_s[wb * 16 + lh * 4 + 2],
                     -0.5f * c2_s[wb * 16 + lh * 4 + 3]};
        frb[(wb * 4 + 0) * 64 + w] = ch8;
        frb[(wb * 4 + 1) * 64 + w] = cl8;
        frb[(wb * 4 + 2) * 64 + w] = a28;
        frb[(wb * 4 + 3) * 64 + w] = __builtin_bit_cast(s16x8, civ);
    }
}

/* ---------- per-group tail (verbatim verified numerics) ---------- */
#define GROUP_TAIL(ACC, G, ROW)                                                        \
  {                                                                                    \
    float q0 = fmaxf(fmaxf(ACC[0][0], ACC[0][1]), ACC[0][2]);                          \
    float q1 = fmaxf(fmaxf(ACC[0][3], ACC[1][0]), ACC[1][1]);                          \
    float q2 = fmaxf(fmaxf(ACC[1][2], ACC[1][3]), ACC[2][0]);                          \
    float q3 = fmaxf(fmaxf(ACC[2][1], ACC[2][2]), ACC[2][3]);                          \
    float q4 = fmaxf(fmaxf(ACC[3][0], ACC[3][1]), ACC[3][2]);                          \
    float m1 = fmaxf(fmaxf(fmaxf(q0, q1), q2), fmaxf(fmaxf(q3, q4), ACC[3][3]));       \
    m1 = fmaxf(m1, __shfl_xor(m1, 16));                                                \
    m1 = fmaxf(m1, __shfl_xor(m1, 32));                                                \
    float thr = m1 - 2e-4f;                                                            \
    int cnt = 0;                                                                       \
    _Pragma("unroll")                                                                  \
    for (int wb = 0; wb < 4; ++wb)                                                     \
      _Pragma("unroll")                                                                \
      for (int r = 0; r < 4; ++r) cnt += (ACC[wb][r] > thr) ? 1 : 0;                   \
    cnt += __shfl_xor(cnt, 16);                                                        \
    cnt += __shfl_xor(cnt, 32);                                                        \
    int wsel = 9999;                                                                   \
    _Pragma("unroll")                                                                  \
    for (int wb = 0; wb < 4; ++wb)                                                     \
      _Pragma("unroll")                                                                \
      for (int r = 0; r < 4; ++r)                                                      \
        if (ACC[wb][r] == m1) wsel = min(wsel, wb * 16 + h * 4 + r);                   \
    wsel = min(wsel, __shfl_xor(wsel, 16));                                            \
    wsel = min(wsel, __shfl_xor(wsel, 32));                                            \
    float mqt = m1 * (-T2K);                                                           \
    float p[16];                                                                       \
    float sum = 0.f;                                                                   \
    _Pragma("unroll")                                                                  \
    for (int wb = 0; wb < 4; ++wb)                                                     \
      _Pragma("unroll")                                                                \
      for (int r = 0; r < 4; ++r) {                                                    \
        p[wb * 4 + r] = __builtin_amdgcn_exp2f(fmaf(T2K, ACC[wb][r], mqt));            \
        sum += p[wb * 4 + r];                                                          \
      }                                                                                \
    sum += __shfl_xor(sum, 16);                                                        \
    sum += __shfl_xor(sum, 32);                                                        \
    float inv = __builtin_amdgcn_rcpf(sum);                                            \
    unsigned int pku[8];                                                               \
    _Pragma("unroll")                                                                  \
    for (int k = 0; k < 8; ++k) pku[k] = cvtpk_bf16(p[2 * k], p[2 * k + 1]);           \
    _Pragma("unroll")                                                                  \
    for (int wb = 0; wb < 4; ++wb) {                                                   \
      uint2 w2; w2.x = pku[2 * wb]; w2.y = pku[2 * wb + 1];                            \
      *(uint2*)&ps_s[wid][G][c][wb * 16 + h * 4] = w2;                                 \
    }                                                                                  \
    s16x8 pb0 = *(const s16x8*)&ps_s[wid][G][c][h * 8];                                \
    s16x8 pb1 = *(const s16x8*)&ps_s[wid][G][c][32 + h * 8];                           \
    float* zout = out + (size_t)(ROW) * DIMS + b * LWORD + h * 4;                      \
    _Pragma("unroll")                                                                  \
    for (int mb = 0; mb < 2; ++mb) {                                                   \
      s16x8 a20 = frag_s[((mb * 2 + 0) * 4 + 2) * 64 + lane];                          \
      s16x8 a21 = frag_s[((mb * 2 + 1) * 4 + 2) * 64 + lane];                          \
      f32x4 z = {0.f, 0.f, 0.f, 0.f};                                                  \
      z = __builtin_amdgcn_mfma_f32_16x16x32_bf16(a20, pb0, z, 0, 0, 0);               \
      z = __builtin_amdgcn_mfma_f32_16x16x32_bf16(a21, pb1, z, 0, 0, 0);               \
      float4 v;                                                                        \
      v.x = z[0] * inv; v.y = z[1] * inv; v.z = z[2] * inv; v.w = z[3] * inv;          \
      *(float4*)(zout + mb * 16) = v;                                                  \
    }                                                                                  \
    if (h == 0) {                                                                      \
      out[Z_ELEMS + (size_t)(ROW) * NBOOKS + b] = (float)wsel;                         \
      if (cnt >= 2) {                                                                  \
        unsigned int pos = atomicAdd(ctr, 1u);                                         \
        if (pos < LIST_CAP) list[pos] = ((unsigned int)(ROW) << 7) | (unsigned int)b;  \
      }                                                                                \
    }                                                                                  \
  }

/* ---------- kernel 2: one-shot blocks, frags in LDS, 2 groups/wave ILP ---------- */
__global__ __launch_bounds__(512, 6) void softpq_mfma(const float* __restrict__ x,
                                                      const s16x8* __restrict__ fr,
                                                      unsigned int* __restrict__ ctr,
                                                      unsigned int* __restrict__ list,
                                                      float* __restrict__ out) {
    __shared__ __align__(16) s16x8 frag_s[1024];                 /* 16384 B */
    __shared__ __align__(16) unsigned short ps_s[8][2][16][72];  /* 36864 B */

    int u = blockIdx.x;                      /* XCD-chunked: 8192 blocks */
    int L = (u & 7) * 1024 + (u >> 3);
    int b  = L >> 6;
    int n0 = (L & 63) * 256;
    int t  = threadIdx.x;
    int lane = t & 63, wid = t >> 6;
    int h = lane >> 4, c = lane & 15;
    int row0 = n0 + wid * 16 + c;            /* group 0: rows n0..n0+127   */
    int row1 = row0 + 128;                   /* group 1: rows n0+128..+255 */

    /* 1) all 4 x loads in flight (HBM latency overlaps staging + barrier) */
    const float* xp0 = x + (size_t)row0 * DIMS + b * LWORD + h * 8;
    const float* xp1 = x + (size_t)row1 * DIMS + b * LWORD + h * 8;
    float4 xa0 = *(const float4*)xp0;
    float4 xb0 = *(const float4*)(xp0 + 4);
    float4 xa1 = *(const float4*)xp1;
    float4 xb1 = *(const float4*)(xp1 + 4);

    /* 2) stage book's 16KB frag record: 512 thr x 32B, conflict-free */
    {
        const s16x8* g = fr + (size_t)b * 1024 + t * 2;
        s16x8 g0 = g[0];
        s16x8 g1 = g[1];
        frag_s[t * 2]     = g0;
        frag_s[t * 2 + 1] = g1;
    }
    __syncthreads();

    /* 3) eager split of both groups (verbatim math) */
    s16x8 xhv0, xlv0, xhv1, xlv1;
    {
        float xf[8] = {xa0.x, xa0.y, xa0.z, xa0.w, xb0.x, xb0.y, xb0.z, xb0.w};
        unsigned int xhu[4], xlu[4];
        #pragma unroll
        for (int j = 0; j < 4; ++j) {
            float f0 = xf[2 * j], f1 = xf[2 * j + 1];
            unsigned int ph = cvtpk_bf16(f0, f1);
            float h0 = __uint_as_float(ph << 16);
            float h1 = __uint_as_float(ph & 0xffff0000u);
            xhu[j] = ph;
            xlu[j] = cvtpk_bf16(f0 - h0, f1 - h1);
        }
        u32x4 thv = {xhu[0], xhu[1], xhu[2], xhu[3]};
        u32x4 tlv = {xlu[0], xlu[1], xlu[2], xlu[3]};
        xhv0 = __builtin_bit_cast(s16x8, thv);
        xlv0 = __builtin_bit_cast(s16x8, tlv);
    }
    {
        float xf[8] = {xa1.x, xa1.y, xa1.z, xa1.w, xb1.x, xb1.y, xb1.z, xb1.w};
        unsigned int xhu[4], xlu[4];
        #pragma unroll
        for (int j = 0; j < 4; ++j) {
            float f0 = xf[2 * j], f1 = xf[2 * j + 1];
            unsigned int ph = cvtpk_bf16(f0, f1);
            float h0 = __uint_as_float(ph << 16);
            float h1 = __uint_as_float(ph & 0xffff0000u);
            xhu[j] = ph;
            xlu[j] = cvtpk_bf16(f0 - h0, f1 - h1);
        }
        u32x4 thv = {xhu[0], xhu[1], xhu[2], xhu[3]};
        u32x4 tlv = {xlu[0], xlu[1], xlu[2], xlu[3]};
        xhv1 = __builtin_bit_cast(s16x8, thv);
        xlv1 = __builtin_bit_cast(s16x8, tlv);
    }

    /* 4) 24 S-MFMAs: one LDS frag read feeds BOTH groups' accumulators */
    f32x4 acc0[4], acc1[4];
    __builtin_amdgcn_s_setprio(1);
    #pragma unroll
    for (int wb = 0; wb < 4; ++wb) {
        s16x8 chf = frag_s[(wb * 4 + 0) * 64 + lane];
        s16x8 clf = frag_s[(wb * 4 + 1) * 64 + lane];
        f32x4 ci  = __builtin_bit_cast(f32x4, frag_s[(wb * 4 + 3) * 64 + lane]);
        f32x4 a0 = ci;
        a0 = __builtin_amdgcn_mfma_f32_16x16x32_bf16(chf, xhv0, a0, 0, 0, 0);
        a0 = __builtin_amdgcn_mfma_f32_16x16x32_bf16(chf, xlv0, a0, 0, 0, 0);
        a0 = __builtin_amdgcn_mfma_f32_16x16x32_bf16(clf, xhv0, a0, 0, 0, 0);
        acc0[wb] = a0;
        f32x4 a1 = ci;
        a1 = __builtin_amdgcn_mfma_f32_16x16x32_bf16(chf, xhv1, a1, 0, 0, 0);
        a1 = __builtin_amdgcn_mfma_f32_16x16x32_bf16(chf, xlv1, a1, 0, 0, 0);
        a1 = __builtin_amdgcn_mfma_f32_16x16x32_bf16(clf, xhv1, a1, 0, 0, 0);
        acc1[wb] = a1;
    }
    __builtin_amdgcn_s_setprio(0);

    /* 5) two independent tails (separate ps_s buffers -> overlapping LDS deps) */
    GROUP_TAIL(acc0, 0, row0)
    GROUP_TAIL(acc1, 1, row1)
}

/* ---------- kernel 3: wave-cooperative np-exact rescan (lane = word) ---------- */
__global__ __launch_bounds__(256) void rescan_wave(const float* __restrict__ x,
                                                   const float* __restrict__ cbT,
                                                   const float* __restrict__ c2T,
                                                   const unsigned int* __restrict__ ctr,
                                                   const unsigned int* __restrict__ list,
                                                   float* __restrict__ out) {
    unsigned int n = *ctr;
    if (n > LIST_CAP) n = LIST_CAP;
    unsigned int wgl = blockIdx.x * 4u + (threadIdx.x >> 6);
    unsigned int nw  = gridDim.x * 4u;
    int lane = threadIdx.x & 63;

    for (unsigned int i = wgl; i < n; i += nw) {
        unsigned int e = list[i];
        int row = (int)(e >> 7);
        int b   = (int)(e & 127u);

        const float* xrow = x + (size_t)row * DIMS + b * LWORD;
        float xr2[LWORD];
        #pragma unroll
        for (int q = 0; q < 8; ++q)
            *(float4*)&xr2[q * 4] = *(const float4*)(xrow + q * 4);
        float sq[LWORD];
        #pragma unroll
        for (int l = 0; l < LWORD; ++l) sq[l] = xr2[l] * xr2[l];
        float x2n = np_sum32(sq);

        const float* cw = cbT + ((size_t)b * NWORDS + lane) * LWORD;
        float cwv[LWORD];
        #pragma unroll
        for (int q = 0; q < 8; ++q)
            *(float4*)&cwv[q * 4] = *(const float4*)(cw + q * 4);
        double a0 = 0.0, a1 = 0.0, a2 = 0.0, a3 = 0.0;
        #pragma unroll
        for (int l = 0; l < 8; ++l) {
            a0 = fma((double)xr2[l],      (double)cwv[l],      a0);
            a1 = fma((double)xr2[l + 8],  (double)cwv[l + 8],  a1);
            a2 = fma((double)xr2[l + 16], (double)cwv[l + 16], a2);
            a3 = fma((double)xr2[l + 24], (double)cwv[l + 24], a3);
        }
        float xcf = (float)((a0 + a1) + (a2 + a3));
        float dnp;
        {
#pragma clang fp contract(off)
            float s1 = x2n + c2T[b * NWORDS + lane];
            float s2 = 2.0f * xcf;
            dnp = s1 - s2;
        }
        float dmin = dnp;
        dmin = fminf(dmin, __shfl_xor(dmin, 1));
        dmin = fminf(dmin, __shfl_xor(dmin, 2));
        dmin = fminf(dmin, __shfl_xor(dmin, 4));
        dmin = fminf(dmin, __shfl_xor(dmin, 8));
        dmin = fminf(dmin, __shfl_xor(dmin, 16));
        dmin = fminf(dmin, __shfl_xor(dmin, 32));
        unsigned long long ball = __ballot(dnp == dmin);
        int wbest = __ffsll((long long)ball) - 1;
        if (lane == 0)
            out[Z_ELEMS + (size_t)row * NBOOKS + b] = (float)wbest;
    }
}

extern "C" void kernel_launch(void* const* d_in, const int* in_sizes, int n_in,
                              void* d_out, int out_size, void* d_ws, size_t ws_size,
                              hipStream_t stream) {
    const float* x = (const float*)d_in[0];
    const float* C = (const float*)d_in[1];
    float* out = (float*)d_out;
    char* ws = (char*)d_ws;
    float* cbT = (float*)(ws + CBT_OFF);
    float* c2T = (float*)(ws + C2T_OFF);
    s16x8* fr  = (s16x8*)(ws + FR_OFF);
    unsigned int* ctr  = (unsigned int*)(ws + CTR_OFF);
    unsigned int* list = (unsigned int*)(ws + LIST_OFF);

    prepC_kernel<<<128, 64, 0, stream>>>(C, cbT, c2T, fr, ctr);
    softpq_mfma<<<8192, 512, 0, stream>>>(x, fr, ctr, list, out);
    rescan_wave<<<512, 256, 0, stream>>>(x, cbT, c2T, ctr, list, out);
}